// Round 1
// baseline (18781.342 us; speedup 1.0000x reference)
//
// LSTM Seq2Seq persistent-kernel implementation for MI355X (gfx950).
//
// Design:
//  - 256 WGs x 256 threads, 1 WG/CU (LDS ~146KB forces it) -> all co-resident.
//  - Batch split into 16 groups of 16 rows; each group served by 16 WGs that
//    split the G=1024 gate dimension k-aligned: WG j owns fm columns
//    {K_j, 256+K_j, 512+K_j, 768+K_j}, K_j = [16j,16j+16). Weights slice lives
//    in LDS (fp32, 98KB), W1/W2 slices too -> no per-step weight streaming.
//  - Per step: fm slice = x_t@Wx + h@Wh + b (x/h operands via uniform scalar
//    loads; weights via ds_read_b128), gates elementwise (c kept in a register
//    per owning thread), h-slice exchanged via agent-scope (sc1) stores/loads,
//    16-WG monotonic atomic barrier per step (counter in d_ws, 128B-spaced).
//  - Decoder: 32 steps, raw gates, then z=h@W1+b1, LayerNorm, relu, y=z@W2+b2
//    with 2 extra barriers/step for h and z exchange.
//  - ws layout: [0,2048) barrier counters; [2048,+512KB) h double buffer
//    [2][256][256] f32; then z buffer [256][256] f32. Total ~770KB.
//  - Counters are zeroed by hipMemsetAsync each launch (graph-replay safe).

#include <hip/hip_runtime.h>
#include <cmath>

#define NTHR 256
#define WPG  16   // workgroups per batch group (barrier width)

__device__ __forceinline__ float sigmoidf_(float x) {
  return 1.0f / (1.0f + expf(-x));
}

__device__ __forceinline__ void arrive_bar(unsigned* cg) {
  __threadfence_block();            // drain this wave's global (sc1) stores
  __syncthreads();                  // all waves drained
  if (threadIdx.x == 0)
    (void)__hip_atomic_fetch_add(cg, 1u, __ATOMIC_RELAXED, __HIP_MEMORY_SCOPE_AGENT);
}

__device__ __forceinline__ void wait_bar(unsigned* cg, unsigned target) {
  if (threadIdx.x == 0) {
    unsigned guard = 0;
    while (__hip_atomic_load(cg, __ATOMIC_RELAXED, __HIP_MEMORY_SCOPE_AGENT) < target) {
      __builtin_amdgcn_s_sleep(2);
      if (++guard > (1u << 20)) break;   // safety valve: avoid infinite GPU hang
    }
    __threadfence();                     // acquire: invalidate L1/L2 (vector)
    asm volatile("s_dcache_inv" ::: "memory");  // invalidate scalar K$ (h via s_load)
  }
  __syncthreads();
}

__global__ __launch_bounds__(NTHR, 1) void lstm_k(
    const float* __restrict__ X,  const float* __restrict__ Wx,
    const float* __restrict__ Wh, const float* __restrict__ Bg,
    const float* __restrict__ W1, const float* __restrict__ B1,
    const float* __restrict__ LNG, const float* __restrict__ LNB,
    const float* __restrict__ W2, const float* __restrict__ B2,
    float* __restrict__ Y, unsigned* __restrict__ CNT,
    float* __restrict__ hbuf, float* __restrict__ zbuf)
{
  // LDS: 98304 + 16640 + 8320 + 2048 + 4160 + 16640 = 146112 B  (<160KB)
  __shared__ float4 w_lds[96][64];    // [k/4][local col]: Wx rows 0..127, Wh rows 128..383
  __shared__ float  w1_lds[16][260];  // transposed W1 slice [zc][k], padded
  __shared__ float  w2_lds[8][260];   // transposed W2 slice [yc][k], padded
  __shared__ float  lng_lds[256], lnb_lds[256];
  __shared__ float  fm_lds[16][65];   // fm slice [row][local col] (+LN stats scratch)
  __shared__ float4 st_lds[16][65];   // decoder staging: h rows / z rows

  const int tid = threadIdx.x;
  const int wg  = blockIdx.x;
  const int g   = wg & 15;        // batch group (0..15)
  const int jm  = wg >> 4;        // column member (0..15)
  const int n0  = g * 16;         // first batch row of group
  const int k0  = jm * 16;        // owned k-slice start
  unsigned* cg  = CNT + g * 32;   // 128B-spaced per-group counter

  // ---- stage weight slices into LDS (one-time) ----
  for (int idx = tid; idx < 384 * 64; idx += NTHR) {
    int kr = idx >> 6, c = idx & 63;
    int gcol = ((c >> 4) << 8) + k0 + (c & 15);     // quad*256 + k0 + kk
    float v = (kr < 128) ? Wx[kr * 1024 + gcol] : Wh[(kr - 128) * 1024 + gcol];
    ((float*)&w_lds[kr >> 2][c])[kr & 3] = v;
  }
  for (int idx = tid; idx < 256 * 16; idx += NTHR) {
    int k = idx >> 4, c = idx & 15;
    w1_lds[c][k] = W1[k * 256 + k0 + c];
  }
  for (int idx = tid; idx < 256 * 8; idx += NTHR) {
    int k = idx >> 3, c = idx & 7;
    w2_lds[c][k] = W2[k * 128 + jm * 8 + c];
  }
  lng_lds[tid] = LNG[tid];
  lnb_lds[tid] = LNB[tid];

  const int c_own = tid & 63;                           // owned local column
  const int rg    = __builtin_amdgcn_readfirstlane(tid >> 6);  // wave id 0..3 (uniform)
  const int gcol_own = ((c_own >> 4) << 8) + k0 + (c_own & 15);
  const float breg = Bg[gcol_own];
  const int gr = tid >> 4, gk = tid & 15;               // gate/LN ownership (r, kk)
  const float b1reg = B1[k0 + gk];
  const float b2reg = (tid < 128) ? B2[jm * 8 + (tid & 7)] : 0.0f;
  float c_reg = 0.0f;                                   // cell state c[n0+gr][k0+gk]

  __syncthreads();

  const size_t XRS = 131072;  // 1024*128, X row stride
  // ================= ENCODER (t = 0..1023) =================
  for (int t = 0; t < 1024; ++t) {
    float a0 = breg, a1 = breg, a2 = breg, a3 = breg;
    // x-part first (independent of h(t-1)) -> hides barrier latency
    {
      const float* x0 = X + (size_t)(n0 + rg     ) * XRS + (size_t)t * 128;
      const float* x1 = X + (size_t)(n0 + rg + 4 ) * XRS + (size_t)t * 128;
      const float* x2 = X + (size_t)(n0 + rg + 8 ) * XRS + (size_t)t * 128;
      const float* x3 = X + (size_t)(n0 + rg + 12) * XRS + (size_t)t * 128;
      #pragma unroll 4
      for (int kc = 0; kc < 32; ++kc) {
        float4 w4 = w_lds[kc][c_own];
        int k = kc << 2;
        a0 = fmaf(x0[k], w4.x, fmaf(x0[k+1], w4.y, fmaf(x0[k+2], w4.z, fmaf(x0[k+3], w4.w, a0))));
        a1 = fmaf(x1[k], w4.x, fmaf(x1[k+1], w4.y, fmaf(x1[k+2], w4.z, fmaf(x1[k+3], w4.w, a1))));
        a2 = fmaf(x2[k], w4.x, fmaf(x2[k+1], w4.y, fmaf(x2[k+2], w4.z, fmaf(x2[k+3], w4.w, a2))));
        a3 = fmaf(x3[k], w4.x, fmaf(x3[k+1], w4.y, fmaf(x3[k+2], w4.z, fmaf(x3[k+3], w4.w, a3))));
      }
    }
    if (t > 0) {
      wait_bar(cg, (unsigned)(WPG * t));   // h(t-1) fully published
      const float* hb = hbuf + (size_t)((t - 1) & 1) * 65536 + (size_t)n0 * 256;
      const float* h0 = hb + (size_t)(rg     ) * 256;
      const float* h1 = hb + (size_t)(rg + 4 ) * 256;
      const float* h2 = hb + (size_t)(rg + 8 ) * 256;
      const float* h3 = hb + (size_t)(rg + 12) * 256;
      #pragma unroll 4
      for (int kc = 0; kc < 64; ++kc) {
        float4 w4 = w_lds[32 + kc][c_own];
        int k = kc << 2;
        a0 = fmaf(h0[k], w4.x, fmaf(h0[k+1], w4.y, fmaf(h0[k+2], w4.z, fmaf(h0[k+3], w4.w, a0))));
        a1 = fmaf(h1[k], w4.x, fmaf(h1[k+1], w4.y, fmaf(h1[k+2], w4.z, fmaf(h1[k+3], w4.w, a1))));
        a2 = fmaf(h2[k], w4.x, fmaf(h2[k+1], w4.y, fmaf(h2[k+2], w4.z, fmaf(h2[k+3], w4.w, a2))));
        a3 = fmaf(h3[k], w4.x, fmaf(h3[k+1], w4.y, fmaf(h3[k+2], w4.z, fmaf(h3[k+3], w4.w, a3))));
      }
    }
    fm_lds[rg     ][c_own] = a0;
    fm_lds[rg + 4 ][c_own] = a1;
    fm_lds[rg + 8 ][c_own] = a2;
    fm_lds[rg + 12][c_own] = a3;
    __syncthreads();
    {
      float iv = fm_lds[gr][gk];
      float fv = fm_lds[gr][16 + gk];
      float ov = fm_lds[gr][32 + gk];
      float gv = fm_lds[gr][48 + gk];
      float si = sigmoidf_(iv), sf = sigmoidf_(fv), so = sigmoidf_(ov);
      float tg = tanhf(gv);
      c_reg = c_reg * sf + si * tg;
      float hv = so * tanhf(c_reg);
      __hip_atomic_store(hbuf + (size_t)(t & 1) * 65536 + (size_t)(n0 + gr) * 256 + k0 + gk,
                         hv, __ATOMIC_RELAXED, __HIP_MEMORY_SCOPE_AGENT);
    }
    arrive_bar(cg);
  }

  // ================= DECODER (s = 0..31) =================
  wait_bar(cg, (unsigned)(WPG * 1024));
  unsigned arrivals = 1024;

  for (int s = 0; s < 32; ++s) {
    const int t = 1024 + s;
    float a0 = breg, a1 = breg, a2 = breg, a3 = breg;
    {
      const float* hb = hbuf + (size_t)((t - 1) & 1) * 65536 + (size_t)n0 * 256;
      const float* h0 = hb + (size_t)(rg     ) * 256;
      const float* h1 = hb + (size_t)(rg + 4 ) * 256;
      const float* h2 = hb + (size_t)(rg + 8 ) * 256;
      const float* h3 = hb + (size_t)(rg + 12) * 256;
      #pragma unroll 4
      for (int kc = 0; kc < 64; ++kc) {
        float4 w4 = w_lds[32 + kc][c_own];
        int k = kc << 2;
        a0 = fmaf(h0[k], w4.x, fmaf(h0[k+1], w4.y, fmaf(h0[k+2], w4.z, fmaf(h0[k+3], w4.w, a0))));
        a1 = fmaf(h1[k], w4.x, fmaf(h1[k+1], w4.y, fmaf(h1[k+2], w4.z, fmaf(h1[k+3], w4.w, a1))));
        a2 = fmaf(h2[k], w4.x, fmaf(h2[k+1], w4.y, fmaf(h2[k+2], w4.z, fmaf(h2[k+3], w4.w, a2))));
        a3 = fmaf(h3[k], w4.x, fmaf(h3[k+1], w4.y, fmaf(h3[k+2], w4.z, fmaf(h3[k+3], w4.w, a3))));
      }
    }
    fm_lds[rg     ][c_own] = a0;
    fm_lds[rg + 4 ][c_own] = a1;
    fm_lds[rg + 8 ][c_own] = a2;
    fm_lds[rg + 12][c_own] = a3;
    __syncthreads();
    {
      // decoder gates are RAW (no sigmoid/tanh on i,f,o,g)
      float iv = fm_lds[gr][gk];
      float fv = fm_lds[gr][16 + gk];
      float ov = fm_lds[gr][32 + gk];
      float gv = fm_lds[gr][48 + gk];
      c_reg = c_reg * fv + iv * gv;
      float hv = ov * tanhf(c_reg);
      __hip_atomic_store(hbuf + (size_t)(t & 1) * 65536 + (size_t)(n0 + gr) * 256 + k0 + gk,
                         hv, __ATOMIC_RELAXED, __HIP_MEMORY_SCOPE_AGENT);
    }
    arrive_bar(cg); ++arrivals;          // B: h(t) published
    wait_bar(cg, WPG * arrivals);

    // stage full h(t) rows into st_lds (coherent loads)
    {
      float* hn = hbuf + (size_t)(t & 1) * 65536 + (size_t)n0 * 256;
      for (int idx = tid; idx < 4096; idx += NTHR) {
        int r = idx >> 8, k = idx & 255;
        ((float*)&st_lds[r][0])[k] =
            __hip_atomic_load(hn + (size_t)r * 256 + k, __ATOMIC_RELAXED, __HIP_MEMORY_SCOPE_AGENT);
      }
    }
    __syncthreads();
    // z slice: z[gr][k0+gk] = h(t)[gr] . W1[:, k0+gk] + b1
    {
      const float4* hr4 = (const float4*)&st_lds[gr][0];
      const float4* w14 = (const float4*)&w1_lds[gk][0];
      float za = b1reg;
      #pragma unroll 4
      for (int kc = 0; kc < 64; ++kc) {
        float4 h4 = hr4[kc], w4 = w14[kc];
        za = fmaf(h4.x, w4.x, fmaf(h4.y, w4.y, fmaf(h4.z, w4.z, fmaf(h4.w, w4.w, za))));
      }
      __hip_atomic_store(zbuf + (size_t)(n0 + gr) * 256 + k0 + gk,
                         za, __ATOMIC_RELAXED, __HIP_MEMORY_SCOPE_AGENT);
    }
    arrive_bar(cg); ++arrivals;          // C: z published
    wait_bar(cg, WPG * arrivals);

    // stage full z rows
    {
      float* zr = zbuf + (size_t)n0 * 256;
      for (int idx = tid; idx < 4096; idx += NTHR) {
        int r = idx >> 8, k = idx & 255;
        ((float*)&st_lds[r][0])[k] =
            __hip_atomic_load(zr + (size_t)r * 256 + k, __ATOMIC_RELAXED, __HIP_MEMORY_SCOPE_AGENT);
      }
    }
    __syncthreads();
    // LayerNorm stats (population var, eps 1e-5)
    {
      const float* zrow = (const float*)&st_lds[gr][0];
      float s1 = 0.0f, s2 = 0.0f;
      #pragma unroll
      for (int u = 0; u < 16; ++u) {
        float v = zrow[gk * 16 + u];
        s1 += v; s2 += v * v;
      }
      #pragma unroll
      for (int d = 1; d < 16; d <<= 1) {
        s1 += __shfl_xor(s1, d);
        s2 += __shfl_xor(s2, d);
      }
      float mu = s1 * (1.0f / 256.0f);
      float var = s2 * (1.0f / 256.0f) - mu * mu;
      float rstd = rsqrtf(var + 1e-5f);
      if (gk == 0) { fm_lds[gr][0] = mu; fm_lds[gr][1] = rstd; }
    }
    __syncthreads();
    // normalize + affine + relu, in place
    #pragma unroll
    for (int rep = 0; rep < 4; ++rep) {
      int idx = tid + NTHR * rep;
      int r = idx >> 6, q = idx & 63;
      float mu = fm_lds[r][0], rs = fm_lds[r][1];
      float4 v = st_lds[r][q];
      int cb = q << 2;
      v.x = fmaxf(fmaf((v.x - mu) * rs, lng_lds[cb    ], lnb_lds[cb    ]), 0.0f);
      v.y = fmaxf(fmaf((v.y - mu) * rs, lng_lds[cb + 1], lnb_lds[cb + 1]), 0.0f);
      v.z = fmaxf(fmaf((v.z - mu) * rs, lng_lds[cb + 2], lnb_lds[cb + 2]), 0.0f);
      v.w = fmaxf(fmaf((v.w - mu) * rs, lng_lds[cb + 3], lnb_lds[cb + 3]), 0.0f);
      st_lds[r][q] = v;
    }
    __syncthreads();
    // y slice: y[r][jm*8+yc] = relu(zn[r]) . W2[:, jm*8+yc] + b2
    if (tid < 128) {
      int r = tid >> 3, yc = tid & 7;
      const float4* zr4 = (const float4*)&st_lds[r][0];
      const float4* w24 = (const float4*)&w2_lds[yc][0];
      float ya = b2reg;
      #pragma unroll 4
      for (int kc = 0; kc < 64; ++kc) {
        float4 z4 = zr4[kc], w4 = w24[kc];
        ya = fmaf(z4.x, w4.x, fmaf(z4.y, w4.y, fmaf(z4.z, w4.z, fmaf(z4.w, w4.w, ya))));
      }
      Y[(size_t)(n0 + r) * 4096 + (size_t)s * 128 + jm * 8 + yc] = ya;
    }
  }
}

extern "C" void kernel_launch(void* const* d_in, const int* in_sizes, int n_in,
                              void* d_out, int out_size, void* d_ws, size_t ws_size,
                              hipStream_t stream) {
  const float* X   = (const float*)d_in[0];
  const float* Wx  = (const float*)d_in[1];
  const float* Wh  = (const float*)d_in[2];
  const float* b   = (const float*)d_in[3];
  const float* W1  = (const float*)d_in[4];
  const float* b1  = (const float*)d_in[5];
  const float* lng = (const float*)d_in[6];
  const float* lnb = (const float*)d_in[7];
  const float* W2  = (const float*)d_in[8];
  const float* b2  = (const float*)d_in[9];
  float* Y = (float*)d_out;

  // ws layout: [0,2048) counters | [2048, +512KB) h double buffer | +256KB z buffer
  unsigned* cnt = (unsigned*)d_ws;
  float* hbuf = (float*)((char*)d_ws + 2048);
  float* zbuf = hbuf + 2 * 256 * 256;
  (void)in_sizes; (void)n_in; (void)out_size; (void)ws_size;

  hipMemsetAsync(d_ws, 0, 2048, stream);   // zero barrier counters every launch
  hipLaunchKernelGGL(lstm_k, dim3(256), dim3(NTHR), 0, stream,
                     X, Wx, Wh, b, W1, b1, lng, lnb, W2, b2, Y, cnt, hbuf, zbuf);
}

// Round 2
// 10002.892 us; speedup vs baseline: 1.8776x; 1.8776x over previous
//
// LSTM Seq2Seq persistent kernel, round 2: L3-coherent exchange via sc0/sc1
// per-access ops (no fences/invalidate), LDS-staged h operands, LDS-prefetched X.
//
//  - 256 WGs x 256 threads, 1 WG/CU (LDS ~151KB). 16 batch groups x 16 WGs.
//  - WG owns 64 fm columns: gcol = (c>>4)*256 + 16*jm + (c&15).
//  - Wave w: kpart p=w&1 (k-half), rowhalf rh=(w>>1)*8. Lane = column.
//    Each thread: 8 partial accumulators (8 rows x 1 col x 192 k).
//  - Weights fp32 in LDS (98KB). X double-buffered in LDS (16KB, prefetched).
//    h(t-1) burst-staged into LDS per step via sc1 loads (coherent at L3).
//  - Barrier: monotonic per-group counter in d_ws (vmcnt(0)-drain + atomic add;
//    spin + syncthreads on wait). No cache invalidates anywhere.
//  - Decoder: same fm path (h only), W1/W2 LDS overlaid on X buffer,
//    z/LN/relu/y head as in round 1 but through the new staging helpers.

#include <hip/hip_runtime.h>
#include <cmath>

#define NTHR 256
#define WPG  16

__device__ __forceinline__ float sigmoidf_(float x) { return 1.0f / (1.0f + expf(-x)); }

// ---- L3-coherent primitives (agent scope, no cache nuking) ----
__device__ __forceinline__ void store_sc(float* p, float v) {
  asm volatile("global_store_dword %0, %1, off sc0 sc1" :: "v"(p), "v"(v) : "memory");
}

// 4 independent coherent 16B loads + single drain; results written to LDS.
__device__ __forceinline__ void stage4_sc(const float* src,
                                          float* d0, float* d1, float* d2, float* d3) {
  float4 a, b, c, d;
  asm volatile(
      "global_load_dwordx4 %0, %4, off sc0 sc1\n\t"
      "global_load_dwordx4 %1, %5, off sc0 sc1\n\t"
      "global_load_dwordx4 %2, %6, off sc0 sc1\n\t"
      "global_load_dwordx4 %3, %7, off sc0 sc1\n\t"
      "s_waitcnt vmcnt(0)"
      : "=&v"(a), "=&v"(b), "=&v"(c), "=&v"(d)
      : "v"(src), "v"(src + 1024), "v"(src + 2048), "v"(src + 3072)
      : "memory");
  *(float4*)d0 = a; *(float4*)d1 = b; *(float4*)d2 = c; *(float4*)d3 = d;
}

__device__ __forceinline__ void arrive_bar(unsigned* cg) {
  asm volatile("s_waitcnt vmcnt(0)" ::: "memory");   // drain sc1 stores to L3
  __syncthreads();
  if (threadIdx.x == 0)
    (void)__hip_atomic_fetch_add(cg, 1u, __ATOMIC_RELAXED, __HIP_MEMORY_SCOPE_AGENT);
}

__device__ __forceinline__ void wait_bar(unsigned* cg, unsigned target) {
  if (threadIdx.x == 0) {
    unsigned guard = 0;
    while (__hip_atomic_load(cg, __ATOMIC_RELAXED, __HIP_MEMORY_SCOPE_AGENT) < target) {
      __builtin_amdgcn_s_sleep(1);
      if (++guard > (1u << 22)) break;   // safety valve
    }
  }
  __syncthreads();
}

__global__ __launch_bounds__(NTHR, 1) void lstm_k(
    const float* __restrict__ X,  const float* __restrict__ Wx,
    const float* __restrict__ Wh, const float* __restrict__ Bg,
    const float* __restrict__ W1, const float* __restrict__ B1,
    const float* __restrict__ LNG, const float* __restrict__ LNB,
    const float* __restrict__ W2, const float* __restrict__ B2,
    float* __restrict__ Y, unsigned* __restrict__ CNT,
    float* __restrict__ hbuf, float* __restrict__ zbuf)
{
  // LDS: 98304 + 16896 + 8192 + 2048 + 25344 + 128 = 150912 B
  __shared__ float4 w_lds[96][64];            // [k/4][col]; rows 0..31 = Wx, 32..95 = Wh
  __shared__ float  h_lds[16][264];           // staged h/z rows (264 = 16B-aligned pad)
  __shared__ float  fm_lds[2][16][64];        // fm partials per kpart
  __shared__ float  lng_lds[256], lnb_lds[256];
  __shared__ __align__(16) unsigned char u_lds[25344];  // X dbuf (enc) | W1/W2 (dec)
  __shared__ float  ln_mu[16], ln_rs[16];

  float* x_lds  = (float*)u_lds;              // [2][16][128]
  float* w1_lds = (float*)u_lds;              // [16][264]
  float* w2_lds = (float*)(u_lds + 16896);    // [8][264]

  const int tid = threadIdx.x;
  const int wg  = blockIdx.x;
  const int g   = wg & 15;
  const int jm  = wg >> 4;
  const int n0  = g * 16;
  const int k0  = jm * 16;
  unsigned* cg  = CNT + g * 32;

  const int lane = tid & 63;
  const int wv   = __builtin_amdgcn_readfirstlane(tid >> 6);
  const int p    = wv & 1;            // k-part
  const int rh   = (wv >> 1) << 3;    // row half base (0 or 8)
  const int c    = lane;              // owned local column

  // ---- one-time weight staging (fp32) ----
  for (int idx = tid; idx < 384 * 64; idx += NTHR) {
    int kr = idx >> 6, cc = idx & 63;
    int gcol = ((cc >> 4) << 8) + k0 + (cc & 15);
    float v = (kr < 128) ? Wx[kr * 1024 + gcol] : Wh[(kr - 128) * 1024 + gcol];
    ((float*)&w_lds[kr >> 2][cc])[kr & 3] = v;
  }
  lng_lds[tid] = LNG[tid];
  lnb_lds[tid] = LNB[tid];

  const int gr = tid >> 4, gk = tid & 15;
  const float bias0 = Bg[          k0 + gk];
  const float bias1 = Bg[256     + k0 + gk];
  const float bias2 = Bg[512     + k0 + gk];
  const float bias3 = Bg[768     + k0 + gk];
  const float b1reg = B1[k0 + gk];
  const float b2reg = (tid < 128) ? B2[jm * 8 + (tid & 7)] : 0.0f;
  float c_reg = 0.0f;

  // stage X(0)
  {
    const float* Xb = X + (size_t)n0 * 131072;
    #pragma unroll
    for (int j = 0; j < 2; ++j) {
      int f = tid + 256 * j, r = f >> 5, d4 = f & 31;
      float4 v = *(const float4*)(Xb + (size_t)r * 131072 + d4 * 4);
      *(float4*)(x_lds + r * 128 + d4 * 4) = v;
    }
  }
  __syncthreads();

  // ================= ENCODER =================
  for (int t = 0; t < 1024; ++t) {
    float acc[8] = {0.f,0.f,0.f,0.f,0.f,0.f,0.f,0.f};

    // x-part from prefetched LDS tile
    {
      const float* xl = x_lds + (t & 1) * 2048 + p * 64;
      #pragma unroll 4
      for (int kc = 0; kc < 16; ++kc) {
        float4 w4 = w_lds[p * 16 + kc][c];
        const float* xb = xl + kc * 4;
        #pragma unroll
        for (int i = 0; i < 8; ++i) {
          float4 o = *(const float4*)(xb + (rh + i) * 128);
          acc[i] = fmaf(o.x, w4.x, fmaf(o.y, w4.y, fmaf(o.z, w4.z, fmaf(o.w, w4.w, acc[i]))));
        }
      }
    }

    if (t > 0) {
      wait_bar(cg, (unsigned)(WPG * t));
      {  // burst-stage h(t-1): 4096 contiguous floats
        const float* hs = hbuf + (size_t)((t - 1) & 1) * 65536 + (size_t)n0 * 256;
        int f = tid, r = f >> 6, kq = f & 63;
        stage4_sc(hs + f * 4,
                  &h_lds[r][kq * 4], &h_lds[r + 4][kq * 4],
                  &h_lds[r + 8][kq * 4], &h_lds[r + 12][kq * 4]);
      }
      __syncthreads();
      {
        const float* hb = &h_lds[0][0] + p * 128;
        #pragma unroll 4
        for (int kc = 0; kc < 32; ++kc) {
          float4 w4 = w_lds[32 + p * 32 + kc][c];
          const float* hx = hb + kc * 4;
          #pragma unroll
          for (int i = 0; i < 8; ++i) {
            float4 o = *(const float4*)(hx + (rh + i) * 264);
            acc[i] = fmaf(o.x, w4.x, fmaf(o.y, w4.y, fmaf(o.z, w4.z, fmaf(o.w, w4.w, acc[i]))));
          }
        }
      }
    }

    #pragma unroll
    for (int i = 0; i < 8; ++i) fm_lds[p][rh + i][c] = acc[i];
    __syncthreads();

    {  // gates
      float fi = fm_lds[0][gr][gk]      + fm_lds[1][gr][gk]      + bias0;
      float ff = fm_lds[0][gr][16 + gk] + fm_lds[1][gr][16 + gk] + bias1;
      float fo = fm_lds[0][gr][32 + gk] + fm_lds[1][gr][32 + gk] + bias2;
      float fg = fm_lds[0][gr][48 + gk] + fm_lds[1][gr][48 + gk] + bias3;
      float si = sigmoidf_(fi), sf = sigmoidf_(ff), so = sigmoidf_(fo);
      float tg = tanhf(fg);
      c_reg = c_reg * sf + si * tg;
      float hv = so * tanhf(c_reg);
      store_sc(hbuf + (size_t)(t & 1) * 65536 + (size_t)(n0 + gr) * 256 + k0 + gk, hv);
    }

    if (t < 1023) {  // prefetch X(t+1) into other buffer
      const float* Xb = X + (size_t)n0 * 131072 + (size_t)(t + 1) * 128;
      float* xl = x_lds + ((t + 1) & 1) * 2048;
      #pragma unroll
      for (int j = 0; j < 2; ++j) {
        int f = tid + 256 * j, r = f >> 5, d4 = f & 31;
        float4 v = *(const float4*)(Xb + (size_t)r * 131072 + d4 * 4);
        *(float4*)(xl + r * 128 + d4 * 4) = v;
      }
    }
    arrive_bar(cg);
  }

  // ---- stage W1/W2 slices into (now free) X region ----
  for (int idx = tid; idx < 256 * 16; idx += NTHR) {
    int k = idx >> 4, cc = idx & 15;
    w1_lds[cc * 264 + k] = W1[k * 256 + k0 + cc];
  }
  for (int idx = tid; idx < 256 * 8; idx += NTHR) {
    int k = idx >> 3, cc = idx & 7;
    w2_lds[cc * 264 + k] = W2[k * 128 + jm * 8 + cc];
  }

  // ================= DECODER =================
  unsigned arr = 1024;
  for (int s = 0; s < 32; ++s) {
    const int t = 1024 + s;
    wait_bar(cg, WPG * arr);
    {  // stage h(t-1)
      const float* hs = hbuf + (size_t)((t - 1) & 1) * 65536 + (size_t)n0 * 256;
      int f = tid, r = f >> 6, kq = f & 63;
      stage4_sc(hs + f * 4,
                &h_lds[r][kq * 4], &h_lds[r + 4][kq * 4],
                &h_lds[r + 8][kq * 4], &h_lds[r + 12][kq * 4]);
    }
    __syncthreads();

    float acc[8] = {0.f,0.f,0.f,0.f,0.f,0.f,0.f,0.f};
    {
      const float* hb = &h_lds[0][0] + p * 128;
      #pragma unroll 4
      for (int kc = 0; kc < 32; ++kc) {
        float4 w4 = w_lds[32 + p * 32 + kc][c];
        const float* hx = hb + kc * 4;
        #pragma unroll
        for (int i = 0; i < 8; ++i) {
          float4 o = *(const float4*)(hx + (rh + i) * 264);
          acc[i] = fmaf(o.x, w4.x, fmaf(o.y, w4.y, fmaf(o.z, w4.z, fmaf(o.w, w4.w, acc[i]))));
        }
      }
    }
    #pragma unroll
    for (int i = 0; i < 8; ++i) fm_lds[p][rh + i][c] = acc[i];
    __syncthreads();

    {  // RAW gates
      float fi = fm_lds[0][gr][gk]      + fm_lds[1][gr][gk]      + bias0;
      float ff = fm_lds[0][gr][16 + gk] + fm_lds[1][gr][16 + gk] + bias1;
      float fo = fm_lds[0][gr][32 + gk] + fm_lds[1][gr][32 + gk] + bias2;
      float fg = fm_lds[0][gr][48 + gk] + fm_lds[1][gr][48 + gk] + bias3;
      c_reg = c_reg * ff + fi * fg;
      float hv = fo * tanhf(c_reg);
      store_sc(hbuf + (size_t)(t & 1) * 65536 + (size_t)(n0 + gr) * 256 + k0 + gk, hv);
    }
    arrive_bar(cg); ++arr;
    wait_bar(cg, WPG * arr);
    {  // stage h(t)
      const float* hs = hbuf + (size_t)(t & 1) * 65536 + (size_t)n0 * 256;
      int f = tid, r = f >> 6, kq = f & 63;
      stage4_sc(hs + f * 4,
                &h_lds[r][kq * 4], &h_lds[r + 4][kq * 4],
                &h_lds[r + 8][kq * 4], &h_lds[r + 12][kq * 4]);
    }
    __syncthreads();

    {  // z = h @ W1 + b1 (own 16 cols)
      float za = b1reg;
      const float* hr = &h_lds[gr][0];
      const float* wr = w1_lds + gk * 264;
      #pragma unroll 4
      for (int kc = 0; kc < 64; ++kc) {
        float4 h4 = *(const float4*)(hr + kc * 4);
        float4 w4 = *(const float4*)(wr + kc * 4);
        za = fmaf(h4.x, w4.x, fmaf(h4.y, w4.y, fmaf(h4.z, w4.z, fmaf(h4.w, w4.w, za))));
      }
      store_sc(zbuf + (size_t)(n0 + gr) * 256 + k0 + gk, za);
    }
    arrive_bar(cg); ++arr;
    wait_bar(cg, WPG * arr);
    {  // stage z (overwrites h_lds; h(t) re-staged from hbuf next step)
      const float* zs = zbuf + (size_t)n0 * 256;
      int f = tid, r = f >> 6, kq = f & 63;
      stage4_sc(zs + f * 4,
                &h_lds[r][kq * 4], &h_lds[r + 4][kq * 4],
                &h_lds[r + 8][kq * 4], &h_lds[r + 12][kq * 4]);
    }
    __syncthreads();

    {  // LayerNorm stats
      const float* zr = &h_lds[gr][0];
      float s1 = 0.f, s2 = 0.f;
      #pragma unroll
      for (int u = 0; u < 16; ++u) { float v = zr[gk * 16 + u]; s1 += v; s2 += v * v; }
      #pragma unroll
      for (int d = 1; d < 16; d <<= 1) { s1 += __shfl_xor(s1, d); s2 += __shfl_xor(s2, d); }
      float mu = s1 * (1.0f / 256.0f);
      float var = s2 * (1.0f / 256.0f) - mu * mu;
      float rstd = rsqrtf(var + 1e-5f);
      if (gk == 0) { ln_mu[gr] = mu; ln_rs[gr] = rstd; }
    }
    __syncthreads();

    #pragma unroll
    for (int rep = 0; rep < 4; ++rep) {  // normalize + affine + relu in place
      int f = tid + 256 * rep, r = f >> 6, kq = f & 63;
      float mu = ln_mu[r], rs = ln_rs[r];
      float4 v = *(float4*)&h_lds[r][kq * 4];
      int cb = kq * 4;
      v.x = fmaxf(fmaf((v.x - mu) * rs, lng_lds[cb    ], lnb_lds[cb    ]), 0.f);
      v.y = fmaxf(fmaf((v.y - mu) * rs, lng_lds[cb + 1], lnb_lds[cb + 1]), 0.f);
      v.z = fmaxf(fmaf((v.z - mu) * rs, lng_lds[cb + 2], lnb_lds[cb + 2]), 0.f);
      v.w = fmaxf(fmaf((v.w - mu) * rs, lng_lds[cb + 3], lnb_lds[cb + 3]), 0.f);
      *(float4*)&h_lds[r][kq * 4] = v;
    }
    __syncthreads();

    if (tid < 128) {  // y = relu(zn) @ W2 + b2 (own 8 cols)
      int r = tid >> 3, yc = tid & 7;
      float ya = b2reg;
      const float* zr = &h_lds[r][0];
      const float* wr = w2_lds + yc * 264;
      #pragma unroll 4
      for (int kc = 0; kc < 64; ++kc) {
        float4 z4 = *(const float4*)(zr + kc * 4);
        float4 w4 = *(const float4*)(wr + kc * 4);
        ya = fmaf(z4.x, w4.x, fmaf(z4.y, w4.y, fmaf(z4.z, w4.z, fmaf(z4.w, w4.w, ya))));
      }
      Y[(size_t)(n0 + r) * 4096 + (size_t)s * 128 + jm * 8 + yc] = ya;
    }
  }
}

extern "C" void kernel_launch(void* const* d_in, const int* in_sizes, int n_in,
                              void* d_out, int out_size, void* d_ws, size_t ws_size,
                              hipStream_t stream) {
  const float* X   = (const float*)d_in[0];
  const float* Wx  = (const float*)d_in[1];
  const float* Wh  = (const float*)d_in[2];
  const float* b   = (const float*)d_in[3];
  const float* W1  = (const float*)d_in[4];
  const float* b1  = (const float*)d_in[5];
  const float* lng = (const float*)d_in[6];
  const float* lnb = (const float*)d_in[7];
  const float* W2  = (const float*)d_in[8];
  const float* b2  = (const float*)d_in[9];
  float* Y = (float*)d_out;

  unsigned* cnt = (unsigned*)d_ws;
  float* hbuf = (float*)((char*)d_ws + 2048);
  float* zbuf = hbuf + 2 * 256 * 256;
  (void)in_sizes; (void)n_in; (void)out_size; (void)ws_size;

  hipMemsetAsync(d_ws, 0, 2048, stream);
  hipLaunchKernelGGL(lstm_k, dim3(256), dim3(NTHR), 0, stream,
                     X, Wx, Wh, b, W1, b1, lng, lnb, W2, b2, Y, cnt, hbuf, zbuf);
}

// Round 3
// 2963.928 us; speedup vs baseline: 6.3366x; 3.3749x over previous
//
// LSTM Seq2Seq persistent kernel, round 3: fp16 hi/lo MFMA for all recurrent
// matmuls, weights held in REGISTERS as pre-packed B-fragments.
//
//  - 256 WGs x 256 threads (4 waves), 1 WG/CU. 16 batch groups x 16 WGs.
//  - WG owns 64 fm columns: gcol(c) = (c>>4)*256 + 16*jm + (c&15).
//    Wave w = N-tile (cols w*16..w*16+16); so wave w owns gate quadrant w.
//  - Weights: per-WG slice (384x64) split v = hi(f16) + lo(f16); stored as
//    MFMA B-fragments in VGPRs (Bh[12], Bl[12] = 96 VGPRs), loaded at setup.
//  - A operand (x(t) k=0..127, h(t-1) k=128..383) staged in LDS as f16 hi/lo,
//    row stride 392 (784B = 16 mod 128 -> conflict-light frag reads).
//  - fm = Ah*Bh + Ah*Bl + Al*Bh (3 acc chains, 36 MFMAs/wave encoder step).
//  - h exchange: sc0/sc1 stores/loads via L3 + per-group monotonic counter
//    barrier in d_ws (same as round 2 - it worked).
//  - Decoder: MFMA on kt 4..11 (Wh part) for fm; vector fp32 head
//    (z=h@W1+b1, LayerNorm, relu, y=z@W2+b2) with W1/W2 in LDS.
//  - LDS ~74KB (A 25KB, fm 4.2KB, hst 17KB, W1/W2 26KB, LN 2KB).

#include <hip/hip_runtime.h>
#include <cmath>

typedef _Float16 f16;
typedef _Float16 f16x4v __attribute__((ext_vector_type(4)));
typedef _Float16 f16x8v __attribute__((ext_vector_type(8)));
typedef float f32x4v __attribute__((ext_vector_type(4)));

#define NTHR 256
#define WPG  16

__device__ __forceinline__ float sigmoidf_(float x) { return 1.0f / (1.0f + expf(-x)); }

__device__ __forceinline__ void store_sc(float* p, float v) {
  asm volatile("global_store_dword %0, %1, off sc0 sc1" :: "v"(p), "v"(v) : "memory");
}

// 4 independent coherent 16B loads (chunks 4KB apart) + single drain.
__device__ __forceinline__ void ld4_sc(const float* p,
                                       float4& a, float4& b, float4& c, float4& d) {
  asm volatile(
      "global_load_dwordx4 %0, %4, off sc0 sc1\n\t"
      "global_load_dwordx4 %1, %5, off sc0 sc1\n\t"
      "global_load_dwordx4 %2, %6, off sc0 sc1\n\t"
      "global_load_dwordx4 %3, %7, off sc0 sc1\n\t"
      "s_waitcnt vmcnt(0)"
      : "=&v"(a), "=&v"(b), "=&v"(c), "=&v"(d)
      : "v"(p), "v"(p + 1024), "v"(p + 2048), "v"(p + 3072)
      : "memory");
}

__device__ __forceinline__ void arrive_bar(unsigned* cg) {
  asm volatile("s_waitcnt vmcnt(0)" ::: "memory");   // drain sc1 stores to L3
  __syncthreads();
  if (threadIdx.x == 0)
    (void)__hip_atomic_fetch_add(cg, 1u, __ATOMIC_RELAXED, __HIP_MEMORY_SCOPE_AGENT);
}

__device__ __forceinline__ void wait_bar(unsigned* cg, unsigned target) {
  if (threadIdx.x == 0) {
    unsigned guard = 0;
    while (__hip_atomic_load(cg, __ATOMIC_RELAXED, __HIP_MEMORY_SCOPE_AGENT) < target) {
      __builtin_amdgcn_s_sleep(1);
      if (++guard > (1u << 22)) break;   // safety valve
    }
  }
  __syncthreads();
}

__device__ __forceinline__ void conv4_wr(float4 v, f16* ph, f16* pl) {
  f16x4v h, l;
  h[0] = (f16)v.x; h[1] = (f16)v.y; h[2] = (f16)v.z; h[3] = (f16)v.w;
  l[0] = (f16)(v.x - (float)h[0]); l[1] = (f16)(v.y - (float)h[1]);
  l[2] = (f16)(v.z - (float)h[2]); l[3] = (f16)(v.w - (float)h[3]);
  *(f16x4v*)ph = h; *(f16x4v*)pl = l;
}

__device__ __forceinline__ void conv8_wr(float4 a, float4 b, f16* ph, f16* pl) {
  f16x8v h, l;
  h[0]=(f16)a.x; h[1]=(f16)a.y; h[2]=(f16)a.z; h[3]=(f16)a.w;
  h[4]=(f16)b.x; h[5]=(f16)b.y; h[6]=(f16)b.z; h[7]=(f16)b.w;
  l[0]=(f16)(a.x-(float)h[0]); l[1]=(f16)(a.y-(float)h[1]);
  l[2]=(f16)(a.z-(float)h[2]); l[3]=(f16)(a.w-(float)h[3]);
  l[4]=(f16)(b.x-(float)h[4]); l[5]=(f16)(b.y-(float)h[5]);
  l[6]=(f16)(b.z-(float)h[6]); l[7]=(f16)(b.w-(float)h[7]);
  *(f16x8v*)ph = h; *(f16x8v*)pl = l;
}

__global__ __launch_bounds__(NTHR, 1) void lstm_k(
    const float* __restrict__ X,  const float* __restrict__ Wx,
    const float* __restrict__ Wh, const float* __restrict__ Bg,
    const float* __restrict__ W1, const float* __restrict__ B1,
    const float* __restrict__ LNG, const float* __restrict__ LNB,
    const float* __restrict__ W2, const float* __restrict__ B2,
    float* __restrict__ Y, unsigned* __restrict__ CNT,
    float* __restrict__ hbuf, float* __restrict__ zbuf)
{
  // LDS total ~74KB
  __shared__ f16   A_hi[16][392];     // A operand hi (row stride 784B = 16 mod 128)
  __shared__ f16   A_lo[16][392];
  __shared__ float fm_lds[16][65];
  __shared__ float hst[16][264];      // decoder head staging (f32)
  __shared__ float w1_lds[16][268];   // W1 slice transposed [col][k]
  __shared__ float w2_lds[8][268];    // W2 slice transposed [col][k]
  __shared__ float lng_lds[256], lnb_lds[256];
  __shared__ float ln_mu[16], ln_rs[16];

  const int tid = threadIdx.x;
  const int wg  = blockIdx.x;
  const int g   = wg & 15;
  const int jm  = wg >> 4;
  const int n0  = g * 16;
  const int k0  = jm * 16;
  unsigned* cg  = CNT + g * 32;

  const int l     = tid & 63;
  const int w     = __builtin_amdgcn_readfirstlane(tid >> 6);  // wave = N-tile
  const int krow0 = (l >> 4) * 8;     // k octet within a 32-k tile
  const int arow  = l & 15;           // A-frag row for this lane

  // ---- B fragments into registers (one-time). Lane l holds
  // B[kt*32 + krow0 + j][w*16 + (l&15)] for j=0..7, split hi/lo f16. ----
  f16x8v Bh[12], Bl[12];
  {
    const int bcol = w * 256 + k0 + (l & 15);   // global fm column
    #pragma unroll
    for (int kt = 0; kt < 12; ++kt) {
      #pragma unroll
      for (int j = 0; j < 8; ++j) {
        int k = kt * 32 + krow0 + j;
        float v = (kt < 4) ? Wx[k * 1024 + bcol] : Wh[(k - 128) * 1024 + bcol];
        f16 hi = (f16)v;
        Bh[kt][j] = hi;
        Bl[kt][j] = (f16)(v - (float)hi);
      }
    }
  }

  // ---- head weights / LN params into LDS (one-time) ----
  for (int idx = tid; idx < 256 * 16; idx += NTHR) {
    int k = idx >> 4, cc = idx & 15;
    w1_lds[cc][k] = W1[k * 256 + k0 + cc];
  }
  for (int idx = tid; idx < 256 * 8; idx += NTHR) {
    int k = idx >> 3, cc = idx & 7;
    w2_lds[cc][k] = W2[k * 128 + jm * 8 + cc];
  }
  lng_lds[tid] = LNG[tid];
  lnb_lds[tid] = LNB[tid];

  const int gr = tid >> 4, gk = tid & 15;
  const float bias0 = Bg[      k0 + gk];
  const float bias1 = Bg[256 + k0 + gk];
  const float bias2 = Bg[512 + k0 + gk];
  const float bias3 = Bg[768 + k0 + gk];
  const float b1reg = B1[k0 + gk];
  const float b2reg = (tid < 128) ? B2[jm * 8 + (tid & 7)] : 0.0f;
  float c_reg = 0.0f;

  // ---- init A: x(0) converted in; h region zeroed ----
  {
    const float* xp = X + (size_t)(n0 + (tid >> 4)) * 131072 + (size_t)(tid & 15) * 8;
    float4 xa = *(const float4*)xp;
    float4 xb = *(const float4*)(xp + 4);
    conv8_wr(xa, xb, &A_hi[tid >> 4][(tid & 15) * 8], &A_lo[tid >> 4][(tid & 15) * 8]);
    f16x8v z8 = {0,0,0,0,0,0,0,0};
    *(f16x8v*)&A_hi[tid >> 4][128 + (tid & 15) * 16] = z8;
    *(f16x8v*)&A_hi[tid >> 4][136 + (tid & 15) * 16] = z8;
    *(f16x8v*)&A_lo[tid >> 4][128 + (tid & 15) * 16] = z8;
    *(f16x8v*)&A_lo[tid >> 4][136 + (tid & 15) * 16] = z8;
  }
  __syncthreads();

  // stage h slice (16 rows x 256) from hbuf into A h-region as f16 hi/lo
  auto stage_h_A = [&](const float* hs) {
    float4 v0, v1, v2, v3;
    ld4_sc(hs, v0, v1, v2, v3);     // chunk c covers rows {c*4 + w}, cols 4l..4l+4
    conv4_wr(v0, &A_hi[w     ][128 + 4 * l], &A_lo[w     ][128 + 4 * l]);
    conv4_wr(v1, &A_hi[w + 4 ][128 + 4 * l], &A_lo[w + 4 ][128 + 4 * l]);
    conv4_wr(v2, &A_hi[w + 8 ][128 + 4 * l], &A_lo[w + 8 ][128 + 4 * l]);
    conv4_wr(v3, &A_hi[w + 12][128 + 4 * l], &A_lo[w + 12][128 + 4 * l]);
  };

  // ================= ENCODER =================
  for (int t = 0; t < 1024; ++t) {
    // prefetch x(t+1) into registers (no dependency; consumed after fm sync)
    float4 xa, xb;
    if (t < 1023) {
      const float* xp = X + (size_t)(n0 + (tid >> 4)) * 131072
                          + (size_t)(t + 1) * 128 + (size_t)(tid & 15) * 8;
      xa = *(const float4*)xp;
      xb = *(const float4*)(xp + 4);
    }

    // A fragments (all 12 k-tiles up front -> one lgkm wait, no chain stalls)
    f16x8v ah[12], al[12];
    {
      const f16* pah = &A_hi[arow][krow0];
      const f16* pal = &A_lo[arow][krow0];
      #pragma unroll
      for (int kt = 0; kt < 12; ++kt) {
        ah[kt] = *(const f16x8v*)(pah + kt * 32);
        al[kt] = *(const f16x8v*)(pal + kt * 32);
      }
    }
    f32x4v ac0 = {0,0,0,0}, ac1 = {0,0,0,0}, ac2 = {0,0,0,0};
    #pragma unroll
    for (int kt = 0; kt < 12; ++kt) {
      ac0 = __builtin_amdgcn_mfma_f32_16x16x32_f16(ah[kt], Bh[kt], ac0, 0, 0, 0);
      ac1 = __builtin_amdgcn_mfma_f32_16x16x32_f16(ah[kt], Bl[kt], ac1, 0, 0, 0);
      ac2 = __builtin_amdgcn_mfma_f32_16x16x32_f16(al[kt], Bh[kt], ac2, 0, 0, 0);
    }
    #pragma unroll
    for (int q = 0; q < 4; ++q)
      fm_lds[(l >> 4) * 4 + q][w * 16 + (l & 15)] = ac0[q] + ac1[q] + ac2[q];
    __syncthreads();

    {  // gates (thread owns fm row gr, k-col gk across 4 quadrants)
      float fi = fm_lds[gr][     gk] + bias0;
      float ff = fm_lds[gr][16 + gk] + bias1;
      float fo = fm_lds[gr][32 + gk] + bias2;
      float fg = fm_lds[gr][48 + gk] + bias3;
      float si = sigmoidf_(fi), sf = sigmoidf_(ff), so = sigmoidf_(fo);
      float tg = tanhf(fg);
      c_reg = c_reg * sf + si * tg;
      float hv = so * tanhf(c_reg);
      store_sc(hbuf + (size_t)(t & 1) * 65536 + (size_t)(n0 + gr) * 256 + k0 + gk, hv);
    }

    // write x(t+1) into A x-region (safe: MFMA reads done at sync above)
    if (t < 1023)
      conv8_wr(xa, xb, &A_hi[tid >> 4][(tid & 15) * 8], &A_lo[tid >> 4][(tid & 15) * 8]);

    arrive_bar(cg);
    if (t < 1023) {
      wait_bar(cg, (unsigned)(WPG * (t + 1)));
      stage_h_A(hbuf + (size_t)(t & 1) * 65536 + (size_t)n0 * 256 + (size_t)tid * 4);
      __syncthreads();
    }
  }

  // ---- stage h(1023) for the decoder ----
  wait_bar(cg, (unsigned)(WPG * 1024));
  stage_h_A(hbuf + (size_t)65536 /* buf 1 */ + (size_t)n0 * 256 + (size_t)tid * 4);
  __syncthreads();
  unsigned arr = 1024;

  // ================= DECODER =================
  for (int s = 0; s < 32; ++s) {
    const int t = 1024 + s;

    // fm = h @ Wh + b  (k-tiles 4..11 only)
    f16x8v ah[8], al[8];
    {
      const f16* pah = &A_hi[arow][128 + krow0];
      const f16* pal = &A_lo[arow][128 + krow0];
      #pragma unroll
      for (int kt = 0; kt < 8; ++kt) {
        ah[kt] = *(const f16x8v*)(pah + kt * 32);
        al[kt] = *(const f16x8v*)(pal + kt * 32);
      }
    }
    f32x4v ac0 = {0,0,0,0}, ac1 = {0,0,0,0}, ac2 = {0,0,0,0};
    #pragma unroll
    for (int kt = 0; kt < 8; ++kt) {
      ac0 = __builtin_amdgcn_mfma_f32_16x16x32_f16(ah[kt], Bh[kt + 4], ac0, 0, 0, 0);
      ac1 = __builtin_amdgcn_mfma_f32_16x16x32_f16(ah[kt], Bl[kt + 4], ac1, 0, 0, 0);
      ac2 = __builtin_amdgcn_mfma_f32_16x16x32_f16(al[kt], Bh[kt + 4], ac2, 0, 0, 0);
    }
    #pragma unroll
    for (int q = 0; q < 4; ++q)
      fm_lds[(l >> 4) * 4 + q][w * 16 + (l & 15)] = ac0[q] + ac1[q] + ac2[q];
    __syncthreads();

    {  // RAW gates (reference decoder applies no activations to i,f,o,g)
      float fi = fm_lds[gr][     gk] + bias0;
      float ff = fm_lds[gr][16 + gk] + bias1;
      float fo = fm_lds[gr][32 + gk] + bias2;
      float fg = fm_lds[gr][48 + gk] + bias3;
      c_reg = c_reg * ff + fi * fg;
      float hv = fo * tanhf(c_reg);
      store_sc(hbuf + (size_t)(t & 1) * 65536 + (size_t)(n0 + gr) * 256 + k0 + gk, hv);
    }
    arrive_bar(cg); ++arr;
    wait_bar(cg, WPG * arr);

    {  // stage h(t): f32 -> hst (for z) AND f16 -> A (for next step's fm)
      const float* hs = hbuf + (size_t)(t & 1) * 65536 + (size_t)n0 * 256 + (size_t)tid * 4;
      float4 v0, v1, v2, v3;
      ld4_sc(hs, v0, v1, v2, v3);
      *(float4*)&hst[w     ][4 * l] = v0;
      *(float4*)&hst[w + 4 ][4 * l] = v1;
      *(float4*)&hst[w + 8 ][4 * l] = v2;
      *(float4*)&hst[w + 12][4 * l] = v3;
      conv4_wr(v0, &A_hi[w     ][128 + 4 * l], &A_lo[w     ][128 + 4 * l]);
      conv4_wr(v1, &A_hi[w + 4 ][128 + 4 * l], &A_lo[w + 4 ][128 + 4 * l]);
      conv4_wr(v2, &A_hi[w + 8 ][128 + 4 * l], &A_lo[w + 8 ][128 + 4 * l]);
      conv4_wr(v3, &A_hi[w + 12][128 + 4 * l], &A_lo[w + 12][128 + 4 * l]);
    }
    __syncthreads();

    {  // z[gr][k0+gk] = h(t)[gr] . W1[:,k0+gk] + b1
      float za = b1reg;
      const float* hr = &hst[gr][0];
      const float* wr = &w1_lds[gk][0];
      #pragma unroll 4
      for (int kc = 0; kc < 64; ++kc) {
        float4 h4 = *(const float4*)(hr + kc * 4);
        float4 w4 = *(const float4*)(wr + kc * 4);
        za = fmaf(h4.x, w4.x, fmaf(h4.y, w4.y, fmaf(h4.z, w4.z, fmaf(h4.w, w4.w, za))));
      }
      store_sc(zbuf + (size_t)(n0 + gr) * 256 + k0 + gk, za);
    }
    arrive_bar(cg); ++arr;
    wait_bar(cg, WPG * arr);

    {  // stage z -> hst
      const float* zs = zbuf + (size_t)n0 * 256 + (size_t)tid * 4;
      float4 v0, v1, v2, v3;
      ld4_sc(zs, v0, v1, v2, v3);
      *(float4*)&hst[w     ][4 * l] = v0;
      *(float4*)&hst[w + 4 ][4 * l] = v1;
      *(float4*)&hst[w + 8 ][4 * l] = v2;
      *(float4*)&hst[w + 12][4 * l] = v3;
    }
    __syncthreads();

    {  // LayerNorm stats
      const float* zr = &hst[gr][0];
      float s1 = 0.f, s2 = 0.f;
      #pragma unroll
      for (int u = 0; u < 16; ++u) { float v = zr[gk * 16 + u]; s1 += v; s2 += v * v; }
      #pragma unroll
      for (int d = 1; d < 16; d <<= 1) { s1 += __shfl_xor(s1, d); s2 += __shfl_xor(s2, d); }
      float mu = s1 * (1.0f / 256.0f);
      float var = s2 * (1.0f / 256.0f) - mu * mu;
      float rstd = rsqrtf(var + 1e-5f);
      if (gk == 0) { ln_mu[gr] = mu; ln_rs[gr] = rstd; }
    }
    __syncthreads();

    #pragma unroll
    for (int rep = 0; rep < 4; ++rep) {  // normalize + affine + relu in place
      int f = tid + 256 * rep, r = f >> 6, kq = f & 63;
      float mu = ln_mu[r], rs = ln_rs[r];
      float4 v = *(float4*)&hst[r][kq * 4];
      int cb = kq * 4;
      v.x = fmaxf(fmaf((v.x - mu) * rs, lng_lds[cb    ], lnb_lds[cb    ]), 0.f);
      v.y = fmaxf(fmaf((v.y - mu) * rs, lng_lds[cb + 1], lnb_lds[cb + 1]), 0.f);
      v.z = fmaxf(fmaf((v.z - mu) * rs, lng_lds[cb + 2], lnb_lds[cb + 2]), 0.f);
      v.w = fmaxf(fmaf((v.w - mu) * rs, lng_lds[cb + 3], lnb_lds[cb + 3]), 0.f);
      *(float4*)&hst[r][kq * 4] = v;
    }
    __syncthreads();

    if (tid < 128) {  // y[r][jm*8+yc] = relu(zn)[r] . W2[:,jm*8+yc] + b2
      int r = tid >> 3, yc = tid & 7;
      float ya = b2reg;
      const float* zr = &hst[r][0];
      const float* wr = &w2_lds[yc][0];
      #pragma unroll 4
      for (int kc = 0; kc < 64; ++kc) {
        float4 z4 = *(const float4*)(zr + kc * 4);
        float4 w4 = *(const float4*)(wr + kc * 4);
        ya = fmaf(z4.x, w4.x, fmaf(z4.y, w4.y, fmaf(z4.z, w4.z, fmaf(z4.w, w4.w, ya))));
      }
      Y[(size_t)(n0 + r) * 4096 + (size_t)s * 128 + jm * 8 + yc] = ya;
    }
    // hst reuse next iteration is safe: two barrier waits intervene.
  }
}

extern "C" void kernel_launch(void* const* d_in, const int* in_sizes, int n_in,
                              void* d_out, int out_size, void* d_ws, size_t ws_size,
                              hipStream_t stream) {
  const float* X   = (const float*)d_in[0];
  const float* Wx  = (const float*)d_in[1];
  const float* Wh  = (const float*)d_in[2];
  const float* b   = (const float*)d_in[3];
  const float* W1  = (const float*)d_in[4];
  const float* b1  = (const float*)d_in[5];
  const float* lng = (const float*)d_in[6];
  const float* lnb = (const float*)d_in[7];
  const float* W2  = (const float*)d_in[8];
  const float* b2  = (const float*)d_in[9];
  float* Y = (float*)d_out;

  unsigned* cnt = (unsigned*)d_ws;
  float* hbuf = (float*)((char*)d_ws + 2048);
  float* zbuf = hbuf + 2 * 256 * 256;
  (void)in_sizes; (void)n_in; (void)out_size; (void)ws_size;

  hipMemsetAsync(d_ws, 0, 2048, stream);
  hipLaunchKernelGGL(lstm_k, dim3(256), dim3(NTHR), 0, stream,
                     X, Wx, Wh, b, W1, b1, lng, lnb, W2, b2, Y, cnt, hbuf, zbuf);
}